// Round 1
// 363.933 us; speedup vs baseline: 1.2409x; 1.2409x over previous
//
#include <hip/hip_runtime.h>
#include <hip/hip_bf16.h>

#define BB 4
#define SS 1024
#define PP 1024
#define EE 1024
#define HH 16
#define DD 64
#define NS 2048          // P + S
#define E3 3072
#define VOFF 8388608     // element offset of V section in present [2,B,H,NS,D]
#define VPAST 4194304    // element offset of V section in layer_past [2,B,H,P,D]

typedef __attribute__((ext_vector_type(8))) short short8;
typedef __attribute__((ext_vector_type(4))) float floatx4;

__device__ __forceinline__ short f2bf(float f) {
    return (short)(__bfloat16_as_ushort(__float2bfloat16(f)));
}

// async global->LDS, 16B per lane; lds ptr must be wave-uniform (HW: base + lane*16)
__device__ __forceinline__ void gload16(const void* g, void* l) {
    __builtin_amdgcn_global_load_lds(
        (const __attribute__((address_space(1))) void*)g,
        (__attribute__((address_space(3))) void*)l, 16, 0, 0);
}

// ---------------- cvt: x -> xb ; layer_past K/V -> kb/vb (bf16, [bh][t][d], t<1024) ----
__global__ __launch_bounds__(256) void cvt_copy_k(
    const float* __restrict__ x, const float* __restrict__ past,
    short* __restrict__ xb, short* __restrict__ kbp, short* __restrict__ vbp)
{
    size_t e0 = ((size_t)blockIdx.x * 256 + threadIdx.x) * 8;
    const float* src;
    short* dst;
    if (e0 < 4194304) {                       // x [4096][1024]
        src = x + e0; dst = xb + e0;
    } else {
        size_t r = e0 - 4194304;
        const float* base = past;
        short* db = kbp;
        if (r >= 4194304) { r -= 4194304; base = past + VPAST; db = vbp; }
        int row = (int)(r >> 6);              // bh*1024 + t
        int bh = row >> 10, t = row & 1023, d = (int)(r & 63);
        src = base + r;
        dst = db + ((size_t)bh * NS + t) * DD + d;
    }
    float4 a0 = *(const float4*)src;
    float4 a1 = *(const float4*)(src + 4);
    short8 s;
    s[0] = f2bf(a0.x); s[1] = f2bf(a0.y); s[2] = f2bf(a0.z); s[3] = f2bf(a0.w);
    s[4] = f2bf(a1.x); s[5] = f2bf(a1.y); s[6] = f2bf(a1.z); s[7] = f2bf(a1.w);
    *(short8*)dst = s;
}

// ---------------- weight transpose+cvt: W[K,N] f32 -> Wt[N,K] bf16 (64x64 LDS tiles) ----
__global__ __launch_bounds__(256) void wtrans_k(
    const float* __restrict__ wa, const float* __restrict__ wp,
    short* __restrict__ wab, short* __restrict__ wpb)
{
    __shared__ short Ts[64][72];
    int bid = blockIdx.x;
    const float* src; short* dst; int n0, k0, Nsrc;
    if (bid < 768) { k0 = (bid & 15) * 64; n0 = (bid >> 4) * 64; src = wa; dst = wab; Nsrc = E3; }
    else { bid -= 768; k0 = (bid & 15) * 64; n0 = (bid >> 4) * 64; src = wp; dst = wpb; Nsrc = EE; }
    int tid = threadIdx.x;
    int r = tid >> 2, c = (tid & 3) * 16;
    const float* s = src + (size_t)(k0 + r) * Nsrc + n0 + c;
    float4 a0 = *(const float4*)(s);
    float4 a1 = *(const float4*)(s + 4);
    float4 a2 = *(const float4*)(s + 8);
    float4 a3 = *(const float4*)(s + 12);
    Ts[c +  0][r] = f2bf(a0.x); Ts[c +  1][r] = f2bf(a0.y);
    Ts[c +  2][r] = f2bf(a0.z); Ts[c +  3][r] = f2bf(a0.w);
    Ts[c +  4][r] = f2bf(a1.x); Ts[c +  5][r] = f2bf(a1.y);
    Ts[c +  6][r] = f2bf(a1.z); Ts[c +  7][r] = f2bf(a1.w);
    Ts[c +  8][r] = f2bf(a2.x); Ts[c +  9][r] = f2bf(a2.y);
    Ts[c + 10][r] = f2bf(a2.z); Ts[c + 11][r] = f2bf(a2.w);
    Ts[c + 12][r] = f2bf(a3.x); Ts[c + 13][r] = f2bf(a3.y);
    Ts[c + 14][r] = f2bf(a3.z); Ts[c + 15][r] = f2bf(a3.w);
    __syncthreads();
    int n = tid >> 2, kc = (tid & 3) * 16;
    short8 v0 = *(const short8*)&Ts[n][kc];
    short8 v1 = *(const short8*)&Ts[n][kc + 8];
    short* d = dst + (size_t)(n0 + n) * EE + k0 + kc;    // K == 1024 for both weights
    *(short8*)d = v0;
    *(short8*)(d + 8) = v1;
}

// ---------------- GEMM (m97-style): C = A[M,1024] @ Bt[N,1024]^T + bias -----------------
// 128x128 tile, BK=32, 4 waves (2x2), global_load_lds staging, bf16 MFMA 16x16x32.
// MODE 0: qkv epilogue (q->qb bf16 prescaled, k/v -> present f32 + kb/vb bf16)
// MODE 1: plain f32 row-major out
template<int MODE>
__global__ __launch_bounds__(256) void gemm_bt_k(
    const short* __restrict__ A,
    const short* __restrict__ Bt,
    const float* __restrict__ bias,
    float* __restrict__ outf,
    short* __restrict__ qb, short* __restrict__ kbp, short* __restrict__ vbp,
    float* __restrict__ present,
    int N)
{
    __shared__ __align__(16) short As[128 * 32];
    __shared__ __align__(16) short Bs[128 * 32];
    int tid = threadIdx.x;
    int wave = tid >> 6, lane = tid & 63;
    int fr = lane & 15, quad = lane >> 4;
    int wm = wave >> 1, wn = wave & 1;
    int m0 = blockIdx.x * 128, n0 = blockIdx.y * 128;

    floatx4 acc[4][4];
#pragma unroll
    for (int m = 0; m < 4; ++m)
#pragma unroll
        for (int n = 0; n < 4; ++n) acc[m][n] = (floatx4){0.f, 0.f, 0.f, 0.f};

    for (int k0 = 0; k0 < 1024; k0 += 32) {
        __syncthreads();
#pragma unroll
        for (int p = 0; p < 2; ++p) {
            int idx = p * 256 + tid;
            int row = idx >> 2, ch = idx & 3;
            gload16(A + (size_t)(m0 + row) * 1024 + k0 + ch * 8,
                    As + (p * 256 + wave * 64) * 8);
            gload16(Bt + (size_t)(n0 + row) * 1024 + k0 + ch * 8,
                    Bs + (p * 256 + wave * 64) * 8);
        }
        __syncthreads();   // drains vmcnt -> gload data visible
        short8 af[4], bf[4];
#pragma unroll
        for (int m = 0; m < 4; ++m)
            af[m] = *(const short8*)(As + (wm * 64 + m * 16 + fr) * 32 + quad * 8);
#pragma unroll
        for (int n = 0; n < 4; ++n)
            bf[n] = *(const short8*)(Bs + (wn * 64 + n * 16 + fr) * 32 + quad * 8);
#pragma unroll
        for (int m = 0; m < 4; ++m)
#pragma unroll
            for (int n = 0; n < 4; ++n)
                acc[m][n] = __builtin_amdgcn_mfma_f32_16x16x32_bf16(af[m], bf[n], acc[m][n], 0, 0, 0);
    }
#pragma unroll
    for (int n = 0; n < 4; ++n) {
        int gc = n0 + wn * 64 + n * 16 + fr;
        float bv = bias[gc];
#pragma unroll
        for (int m = 0; m < 4; ++m) {
#pragma unroll
            for (int r = 0; r < 4; ++r) {
                int gr = m0 + wm * 64 + m * 16 + quad * 4 + r;
                float val = acc[m][n][r] + bv;
                if (MODE == 1) {
                    outf[(size_t)gr * N + gc] = val;
                } else {
                    int sec = gc >> 10, h = (gc >> 6) & 15, d = gc & 63;
                    int b = gr >> 10, sq = gr & 1023;
                    size_t bh = (size_t)(b * HH + h);
                    if (sec == 0) {
                        qb[(bh * SS + sq) * DD + d] = f2bf(val * 0.125f);  // fold 1/sqrt(D)
                    } else {
                        size_t off = (bh * NS + PP + sq) * DD + d;
                        if (sec == 1) { present[off] = val;        kbp[off] = f2bf(val); }
                        else          { present[VOFF + off] = val; vbp[off] = f2bf(val); }
                    }
                }
            }
        }
    }
}

// ---------------- flash attention: all-bf16 inputs, K staged via gload_lds + XOR swizzle --
__global__ __launch_bounds__(256) void flash_attn_k(
    const short* __restrict__ qb, const short* __restrict__ kbp,
    const short* __restrict__ vbp, short* __restrict__ ab)
{
    __shared__ __align__(16) short Ks[64 * 64];      // [key][d], chunk-XOR-swizzled
    __shared__ __align__(16) short Vs[64][72];       // transposed: [d][key]
    __shared__ __align__(16) short Ps[4][16][72];    // per-wave P round-trip

    int tid = threadIdx.x;
    int wave = tid >> 6, lane = tid & 63;
    int fr = lane & 15, quad = lane >> 4;
    int bh = blockIdx.x >> 4;
    int q0 = (blockIdx.x & 15) * 64;

    const short* qrow = qb + ((size_t)bh * SS + q0 + wave * 16 + fr) * DD;
    short8 qf[2];
    qf[0] = *(const short8*)(qrow + quad * 8);
    qf[1] = *(const short8*)(qrow + 32 + quad * 8);

    const short* kbase = kbp + (size_t)bh * NS * DD;
    const short* vbase = vbp + (size_t)bh * NS * DD;

    float m_r[4], l_r[4];
    floatx4 Oacc[4];
#pragma unroll
    for (int r = 0; r < 4; ++r) { m_r[r] = -1e30f; l_r[r] = 0.f; }
#pragma unroll
    for (int c2 = 0; c2 < 4; ++c2) Oacc[c2] = (floatx4){0.f, 0.f, 0.f, 0.f};

    int vkey = tid & 63, vd0 = (tid >> 6) * 16;

    int nchunks = 17 + (q0 >> 6);
    for (int c = 0; c < nchunks; ++c) {
        int t0 = c * 64;
        const short* kc = kbase + (size_t)t0 * DD;
        const short* vc = vbase + (size_t)t0 * DD;
        __syncthreads();
        // K: linear LDS dest, inverse-swizzled global source (16B-chunk XOR within row)
#pragma unroll
        for (int p = 0; p < 2; ++p) {
            int idx = p * 256 + tid;
            int row = idx >> 3, ch = idx & 7;
            gload16(kc + (size_t)row * DD + ((ch ^ (row & 7)) * 8),
                    Ks + (p * 256 + wave * 64) * 8);
        }
        // V: bf16 register copy, transposed scalar LDS writes
        {
            const short* src = vc + (size_t)vkey * DD + vd0;
            short8 s0 = *(const short8*)src;
            short8 s1 = *(const short8*)(src + 8);
#pragma unroll
            for (int i = 0; i < 8; ++i) {
                Vs[vd0 + i][vkey] = s0[i];
                Vs[vd0 + 8 + i][vkey] = s1[i];
            }
        }
        __syncthreads();

        // ---- S[16q x 64keys] = Q K^T (scale pre-folded into q) ----
        floatx4 S[4];
#pragma unroll
        for (int ct = 0; ct < 4; ++ct) S[ct] = (floatx4){0.f, 0.f, 0.f, 0.f};
#pragma unroll
        for (int ct = 0; ct < 4; ++ct) {
            int row = ct * 16 + fr;
#pragma unroll
            for (int ks = 0; ks < 2; ++ks) {
                short8 kf = *(const short8*)(Ks + row * 64 + (((ks * 4 + quad) ^ (row & 7)) * 8));
                S[ct] = __builtin_amdgcn_mfma_f32_16x16x32_bf16(qf[ks], kf, S[ct], 0, 0, 0);
            }
        }
        if (c == nchunks - 1) {
#pragma unroll
            for (int ct = 0; ct < 4; ++ct)
#pragma unroll
                for (int r = 0; r < 4; ++r)
                    if (ct * 16 + fr > wave * 16 + quad * 4 + r) S[ct][r] = -1e30f;
        }
        // ---- online softmax ----
#pragma unroll
        for (int r = 0; r < 4; ++r) {
            float mx = fmaxf(fmaxf(S[0][r], S[1][r]), fmaxf(S[2][r], S[3][r]));
#pragma unroll
            for (int o = 1; o <= 8; o <<= 1) mx = fmaxf(mx, __shfl_xor(mx, o, 64));
            float mnew = fmaxf(m_r[r], mx);
            float sum = 0.f;
#pragma unroll
            for (int ct = 0; ct < 4; ++ct) {
                float p = exp2f((S[ct][r] - mnew) * 1.44269504f);
                S[ct][r] = p;
                sum += p;
            }
#pragma unroll
            for (int o = 1; o <= 8; o <<= 1) sum += __shfl_xor(sum, o, 64);
            float alpha = exp2f((m_r[r] - mnew) * 1.44269504f);
            l_r[r] = l_r[r] * alpha + sum;
            m_r[r] = mnew;
#pragma unroll
            for (int c2 = 0; c2 < 4; ++c2) Oacc[c2][r] *= alpha;
        }
        // ---- P: C-layout -> A-layout via per-wave LDS ----
#pragma unroll
        for (int ct = 0; ct < 4; ++ct)
#pragma unroll
            for (int r = 0; r < 4; ++r)
                Ps[wave][quad * 4 + r][ct * 16 + fr] = f2bf(S[ct][r]);
#pragma unroll
        for (int ks = 0; ks < 2; ++ks) {
            short8 pf = *(const short8*)(&Ps[wave][fr][ks * 32 + quad * 8]);
#pragma unroll
            for (int c2 = 0; c2 < 4; ++c2) {
                short8 vf = *(const short8*)(&Vs[c2 * 16 + fr][ks * 32 + quad * 8]);
                Oacc[c2] = __builtin_amdgcn_mfma_f32_16x16x32_bf16(pf, vf, Oacc[c2], 0, 0, 0);
            }
        }
    }
    // ---- epilogue: O / l -> ab bf16 [B,S,E] (A-matrix of the projection GEMM) ----
    int b = bh >> 4, h = bh & 15;
#pragma unroll
    for (int r = 0; r < 4; ++r) {
        float inv = 1.f / l_r[r];
        int q = q0 + wave * 16 + quad * 4 + r;
        short* dst = ab + ((size_t)(b * SS + q)) * EE + h * DD;
#pragma unroll
        for (int c2 = 0; c2 < 4; ++c2) dst[c2 * 16 + fr] = f2bf(Oacc[c2][r] * inv);
    }
}

// ---------------- final: copy layer_past into present's past slots ----------------
__global__ __launch_bounds__(256) void copy_past_k(
    const float* __restrict__ past,
    float* __restrict__ present)
{
    int idx = blockIdx.x * 256 + threadIdx.x;
    size_t e0 = (size_t)idx * 8;
    int r = (int)(e0 >> 6);
    int off = (int)(e0 & 63);
    int t = r & (PP - 1);
    int bh = r >> 10;
    size_t dstoff = (((size_t)bh * NS) + t) * DD + off;
    *(float4*)(present + dstoff)     = *(const float4*)(past + e0);
    *(float4*)(present + dstoff + 4) = *(const float4*)(past + e0 + 4);
}

extern "C" void kernel_launch(void* const* d_in, const int* in_sizes, int n_in,
                              void* d_out, int out_size, void* d_ws, size_t ws_size,
                              hipStream_t stream) {
    const float* x      = (const float*)d_in[0];
    const float* past   = (const float*)d_in[1];
    const float* w_attn = (const float*)d_in[2];
    const float* b_attn = (const float*)d_in[3];
    const float* w_proj = (const float*)d_in[4];
    const float* b_proj = (const float*)d_in[5];
    float* out = (float*)d_out;
    float* present = out + (size_t)BB * SS * EE;

    // workspace (bf16 staging), 64 MiB total
    short* ws  = (short*)d_ws;
    short* xb  = ws;                 // [4096][1024]            4,194,304
    short* wab = xb  + 4194304;      // w_attn^T [3072][1024]   3,145,728
    short* wpb = wab + 3145728;      // w_proj^T [1024][1024]   1,048,576
    short* qb  = wpb + 1048576;      // q [B,H,S,D] prescaled   4,194,304
    short* kbp = qb  + 4194304;      // K [B,H,NS,D]            8,388,608
    short* vbp = kbp + 8388608;      // V [B,H,NS,D]            8,388,608
    short* ab  = vbp + 8388608;      // attn out [B,S,E]        4,194,304

    cvt_copy_k<<<6144, 256, 0, stream>>>(x, past, xb, kbp, vbp);
    wtrans_k<<<1024, 256, 0, stream>>>(w_attn, w_proj, wab, wpb);
    gemm_bt_k<0><<<dim3(32, 24), 256, 0, stream>>>(xb, wab, b_attn, nullptr,
                                                   qb, kbp, vbp, present, E3);
    flash_attn_k<<<BB * HH * (SS / 64), 256, 0, stream>>>(qb, kbp, vbp, ab);
    gemm_bt_k<1><<<dim3(32, 8), 256, 0, stream>>>(ab, wpb, b_proj, out,
                                                  nullptr, nullptr, nullptr, nullptr, EE);
    copy_past_k<<<(2 * BB * HH * PP * DD) / (256 * 8), 256, 0, stream>>>(past, present);
}

// Round 2
// 311.638 us; speedup vs baseline: 1.4491x; 1.1678x over previous
//
#include <hip/hip_runtime.h>
#include <hip/hip_bf16.h>

#define BB 4
#define SS 1024
#define PP 1024
#define EE 1024
#define HH 16
#define DD 64
#define NS 2048          // P + S
#define E3 3072
#define VOFF 8388608     // element offset of V section in present [2,B,H,NS,D]
#define VPAST 4194304    // element offset of V section in layer_past [2,B,H,P,D]

typedef __attribute__((ext_vector_type(8))) short short8;
typedef __attribute__((ext_vector_type(4))) float floatx4;
typedef __attribute__((ext_vector_type(16))) float floatx16;
typedef __attribute__((ext_vector_type(4))) unsigned uintx4;

__device__ __forceinline__ short f2bf(float f) {
    return (short)(__bfloat16_as_ushort(__float2bfloat16(f)));
}

__device__ __forceinline__ unsigned cvtpk(float lo, float hi) {
    unsigned r;
    asm("v_cvt_pk_bf16_f32 %0, %1, %2" : "=v"(r) : "v"(lo), "v"(hi));
    return r;
}

// exchange: a.row1 <-> b.row0  =>  a = [a_lo | b_lo↑], b = [a_hi↓ | b_hi]
__device__ __forceinline__ void plswap(unsigned &a, unsigned &b) {
    asm("v_permlane32_swap_b32 %0, %1" : "+v"(a), "+v"(b));
}

// async global->LDS, 16B per lane; lds ptr must be wave-uniform (HW: base + lane*16)
__device__ __forceinline__ void gload16(const void* g, void* l) {
    __builtin_amdgcn_global_load_lds(
        (const __attribute__((address_space(1))) void*)g,
        (__attribute__((address_space(3))) void*)l, 16, 0, 0);
}

// ---- cvt: x -> xb ; past K/V -> kb/vb bf16 AND present f32 past-slots (copy merged) ----
__global__ __launch_bounds__(256) void cvt_copy_k(
    const float* __restrict__ x, const float* __restrict__ past,
    short* __restrict__ xb, short* __restrict__ kbp, short* __restrict__ vbp,
    float* __restrict__ present)
{
    size_t e0 = ((size_t)blockIdx.x * 256 + threadIdx.x) * 8;
    if (e0 < 4194304) {                       // x [4096][1024]
        float4 a0 = *(const float4*)(x + e0);
        float4 a1 = *(const float4*)(x + e0 + 4);
        short8 s;
        s[0] = f2bf(a0.x); s[1] = f2bf(a0.y); s[2] = f2bf(a0.z); s[3] = f2bf(a0.w);
        s[4] = f2bf(a1.x); s[5] = f2bf(a1.y); s[6] = f2bf(a1.z); s[7] = f2bf(a1.w);
        *(short8*)(xb + e0) = s;
    } else {
        size_t r = e0 - 4194304;
        int sec = (r >= 4194304);             // 0: K, 1: V
        if (sec) r -= 4194304;
        const float* src = past + (sec ? VPAST : 0) + r;
        int row = (int)(r >> 6);              // bh*1024 + t
        int bh = row >> 10, t = row & 1023, d = (int)(r & 63);
        size_t off = ((size_t)bh * NS + t) * DD + d;
        float4 a0 = *(const float4*)src;
        float4 a1 = *(const float4*)(src + 4);
        short8 s;
        s[0] = f2bf(a0.x); s[1] = f2bf(a0.y); s[2] = f2bf(a0.z); s[3] = f2bf(a0.w);
        s[4] = f2bf(a1.x); s[5] = f2bf(a1.y); s[6] = f2bf(a1.z); s[7] = f2bf(a1.w);
        *(short8*)((sec ? vbp : kbp) + off) = s;
        float* pd = present + (sec ? VOFF : 0) + off;
        *(float4*)(pd)     = a0;
        *(float4*)(pd + 4) = a1;
    }
}

// ---------------- weight transpose+cvt: W[K,N] f32 -> Wt[N,K] bf16 (64x64 LDS tiles) ----
__global__ __launch_bounds__(256) void wtrans_k(
    const float* __restrict__ wa, const float* __restrict__ wp,
    short* __restrict__ wab, short* __restrict__ wpb)
{
    __shared__ short Ts[64][72];
    int bid = blockIdx.x;
    const float* src; short* dst; int n0, k0, Nsrc;
    if (bid < 768) { k0 = (bid & 15) * 64; n0 = (bid >> 4) * 64; src = wa; dst = wab; Nsrc = E3; }
    else { bid -= 768; k0 = (bid & 15) * 64; n0 = (bid >> 4) * 64; src = wp; dst = wpb; Nsrc = EE; }
    int tid = threadIdx.x;
    int r = tid >> 2, c = (tid & 3) * 16;
    const float* s = src + (size_t)(k0 + r) * Nsrc + n0 + c;
    float4 a0 = *(const float4*)(s);
    float4 a1 = *(const float4*)(s + 4);
    float4 a2 = *(const float4*)(s + 8);
    float4 a3 = *(const float4*)(s + 12);
    Ts[c +  0][r] = f2bf(a0.x); Ts[c +  1][r] = f2bf(a0.y);
    Ts[c +  2][r] = f2bf(a0.z); Ts[c +  3][r] = f2bf(a0.w);
    Ts[c +  4][r] = f2bf(a1.x); Ts[c +  5][r] = f2bf(a1.y);
    Ts[c +  6][r] = f2bf(a1.z); Ts[c +  7][r] = f2bf(a1.w);
    Ts[c +  8][r] = f2bf(a2.x); Ts[c +  9][r] = f2bf(a2.y);
    Ts[c + 10][r] = f2bf(a2.z); Ts[c + 11][r] = f2bf(a2.w);
    Ts[c + 12][r] = f2bf(a3.x); Ts[c + 13][r] = f2bf(a3.y);
    Ts[c + 14][r] = f2bf(a3.z); Ts[c + 15][r] = f2bf(a3.w);
    __syncthreads();
    int n = tid >> 2, kc = (tid & 3) * 16;
    short8 v0 = *(const short8*)&Ts[n][kc];
    short8 v1 = *(const short8*)&Ts[n][kc + 8];
    short* d = dst + (size_t)(n0 + n) * EE + k0 + kc;    // K == 1024 for both weights
    *(short8*)d = v0;
    *(short8*)(d + 8) = v1;
}

// ---------------- GEMM (m97-style): C = A[M,1024] @ Bt[N,1024]^T + bias -----------------
template<int MODE>
__global__ __launch_bounds__(256) void gemm_bt_k(
    const short* __restrict__ A,
    const short* __restrict__ Bt,
    const float* __restrict__ bias,
    float* __restrict__ outf,
    short* __restrict__ qb, short* __restrict__ kbp, short* __restrict__ vbp,
    float* __restrict__ present,
    int N)
{
    __shared__ __align__(16) short As[128 * 32];
    __shared__ __align__(16) short Bs[128 * 32];
    int tid = threadIdx.x;
    int wave = tid >> 6, lane = tid & 63;
    int fr = lane & 15, quad = lane >> 4;
    int wm = wave >> 1, wn = wave & 1;
    // XCD-chunked bijective swizzle: each XCD gets a contiguous bx-range (A-panels L2-resident)
    int hw = blockIdx.y * gridDim.x + blockIdx.x;
    int nwg = gridDim.x * gridDim.y;                // 768 or 256, both % 8 == 0
    int work = (hw & 7) * (nwg >> 3) + (hw >> 3);
    int bx = work / gridDim.y, by = work - bx * gridDim.y;
    int m0 = bx * 128, n0 = by * 128;

    floatx4 acc[4][4];
#pragma unroll
    for (int m = 0; m < 4; ++m)
#pragma unroll
        for (int n = 0; n < 4; ++n) acc[m][n] = (floatx4){0.f, 0.f, 0.f, 0.f};

    for (int k0 = 0; k0 < 1024; k0 += 32) {
        __syncthreads();
#pragma unroll
        for (int p = 0; p < 2; ++p) {
            int idx = p * 256 + tid;
            int row = idx >> 2, ch = idx & 3;
            gload16(A + (size_t)(m0 + row) * 1024 + k0 + ch * 8,
                    As + (p * 256 + wave * 64) * 8);
            gload16(Bt + (size_t)(n0 + row) * 1024 + k0 + ch * 8,
                    Bs + (p * 256 + wave * 64) * 8);
        }
        __syncthreads();
        short8 af[4], bf[4];
#pragma unroll
        for (int m = 0; m < 4; ++m)
            af[m] = *(const short8*)(As + (wm * 64 + m * 16 + fr) * 32 + quad * 8);
#pragma unroll
        for (int n = 0; n < 4; ++n)
            bf[n] = *(const short8*)(Bs + (wn * 64 + n * 16 + fr) * 32 + quad * 8);
#pragma unroll
        for (int m = 0; m < 4; ++m)
#pragma unroll
            for (int n = 0; n < 4; ++n)
                acc[m][n] = __builtin_amdgcn_mfma_f32_16x16x32_bf16(af[m], bf[n], acc[m][n], 0, 0, 0);
    }
#pragma unroll
    for (int n = 0; n < 4; ++n) {
        int gc = n0 + wn * 64 + n * 16 + fr;
        float bv = bias[gc];
#pragma unroll
        for (int m = 0; m < 4; ++m) {
#pragma unroll
            for (int r = 0; r < 4; ++r) {
                int gr = m0 + wm * 64 + m * 16 + quad * 4 + r;
                float val = acc[m][n][r] + bv;
                if (MODE == 1) {
                    outf[(size_t)gr * N + gc] = val;
                } else {
                    int sec = gc >> 10, h = (gc >> 6) & 15, d = gc & 63;
                    int b = gr >> 10, sq = gr & 1023;
                    size_t bh = (size_t)(b * HH + h);
                    if (sec == 0) {
                        qb[(bh * SS + sq) * DD + d] = f2bf(val * 0.125f);  // fold 1/sqrt(D)
                    } else {
                        size_t off = (bh * NS + PP + sq) * DD + d;
                        if (sec == 1) { present[off] = val;        kbp[off] = f2bf(val); }
                        else          { present[VOFF + off] = val; vbp[off] = f2bf(val); }
                    }
                }
            }
        }
    }
}

// ------------- flash attention: swapped-QK^T 32x32 MFMA, in-register softmax -------------
// 4 waves x 32 q-rows = 128 q/block. S^T = mfma(K, Q^T): lane owns q = lane&31
// (keys split lane/lane^32). P -> PV B-operand via cvt_pk + permlane32_swap (T12).
// PV swapped: O^T = mfma(V^T, P^T) so O columns = q -> per-lane alpha/1/l scaling.
__global__ __launch_bounds__(256) void flash_attn_k(
    const short* __restrict__ qb, const short* __restrict__ kbp,
    const short* __restrict__ vbp, short* __restrict__ ab)
{
    __shared__ __align__(16) short smem[9216];
    short* Ks = smem;            // [64][64] bf16, 16B-chunk XOR-swizzled by (row&7)
    short* Vs = smem + 4096;     // [64 d][72] = V^T (padded)

    int tid = threadIdx.x;
    int wave = tid >> 6, lane = tid & 63;
    int qcol = lane & 31, hi = lane >> 5;

    // XCD-chunked swizzle: XCD n -> bh in [n*8, n*8+8) (4 MB K/V per XCD L2)
    int bid = blockIdx.x;
    int work = (bid & 7) * 64 + (bid >> 3);
    int bh = work >> 3;
    int q0 = (work & 7) * 128;

    // Q^T B-fragments: lane holds Q[q = qcol][d = d0*16 + hi*8 + e]
    const short* qrow = qb + ((size_t)bh * SS + q0 + wave * 32 + qcol) * DD + hi * 8;
    short8 qf[4];
#pragma unroll
    for (int i = 0; i < 4; ++i) qf[i] = *(const short8*)(qrow + i * 16);

    const short* kbase = kbp + (size_t)bh * NS * DD;
    const short* vbase = vbp + (size_t)bh * NS * DD;

    float m_r = -1e30f, l_r = 0.f;
    floatx16 Oa[2];
#pragma unroll
    for (int dt = 0; dt < 2; ++dt)
#pragma unroll
        for (int r = 0; r < 16; ++r) Oa[dt][r] = 0.f;

    int vkey = lane, vd0 = wave * 16;
    int qminw = PP + q0 + wave * 32;
    int qmaxw = qminw + 31;
    const float L2E = 1.44269504f;

    int nchunks = 18 + (q0 >> 6);
    for (int c = 0; c < nchunks; ++c) {
        int t0 = c * 64;
        __syncthreads();
        // stage K: linear LDS dest, inverse-swizzled global source
        const short* kc = kbase + (size_t)t0 * DD;
#pragma unroll
        for (int p = 0; p < 2; ++p) {
            int idx = p * 256 + tid;
            int row = idx >> 3, ch = idx & 7;
            gload16(kc + row * 64 + ((ch ^ (row & 7)) * 8),
                    Ks + (p * 256 + wave * 64) * 8);
        }
        // stage V^T (bf16 reg copy + transposed b16 writes; 2B pairs merge per dword)
        {
            const short* src = vbase + ((size_t)t0 + vkey) * DD + vd0;
            short8 s0 = *(const short8*)src;
            short8 s1 = *(const short8*)(src + 8);
#pragma unroll
            for (int i = 0; i < 8; ++i) {
                Vs[(vd0 + i) * 72 + vkey] = s0[i];
                Vs[(vd0 + 8 + i) * 72 + vkey] = s1[i];
            }
        }
        __syncthreads();
        if (t0 > qmaxw) continue;          // fully masked for this wave (barriers done)

        // ---- S^T[key][q] = K·Q^T ----
        floatx16 Sa[2];
#pragma unroll
        for (int ct = 0; ct < 2; ++ct)
#pragma unroll
            for (int r = 0; r < 16; ++r) Sa[ct][r] = 0.f;
#pragma unroll
        for (int ct = 0; ct < 2; ++ct) {
            int key = ct * 32 + qcol;
            int rbase = key * 64, rx = key & 7;
#pragma unroll
            for (int d0 = 0; d0 < 4; ++d0) {
                short8 kf = *(const short8*)(Ks + rbase + (((d0 * 2 + hi) ^ rx) * 8));
                Sa[ct] = __builtin_amdgcn_mfma_f32_32x32x16_bf16(kf, qf[d0], Sa[ct], 0, 0, 0);
            }
        }
        // causal mask (only near-diagonal chunks)
        if (t0 + 63 > qminw) {
            int qa = qminw + qcol;
#pragma unroll
            for (int ct = 0; ct < 2; ++ct)
#pragma unroll
                for (int r = 0; r < 16; ++r) {
                    int ka = t0 + ct * 32 + (r & 3) + 8 * (r >> 2) + 4 * hi;
                    if (ka > qa) Sa[ct][r] = -1e30f;
                }
        }
        // ---- in-register online softmax (lane owns q = qcol; partner = lane^32) ----
        float mx0 = Sa[0][0], mx1 = Sa[0][1], mx2 = Sa[0][2], mx3 = Sa[0][3];
#pragma unroll
        for (int ct = 0; ct < 2; ++ct)
#pragma unroll
            for (int r = (ct ? 0 : 4); r < 16; r += 4) {
                mx0 = fmaxf(mx0, Sa[ct][r]);
                mx1 = fmaxf(mx1, Sa[ct][r + 1]);
                mx2 = fmaxf(mx2, Sa[ct][r + 2]);
                mx3 = fmaxf(mx3, Sa[ct][r + 3]);
            }
        float mx = fmaxf(fmaxf(mx0, mx1), fmaxf(mx2, mx3));
        mx = fmaxf(mx, __shfl_xor(mx, 32, 64));
        float mnew = fmaxf(m_r, mx);
        float base = mnew * L2E;
        float s0 = 0.f, s1 = 0.f, s2 = 0.f, s3 = 0.f;
#pragma unroll
        for (int ct = 0; ct < 2; ++ct)
#pragma unroll
            for (int r = 0; r < 16; r += 4) {
                float p0 = exp2f(Sa[ct][r] * L2E - base);
                float p1 = exp2f(Sa[ct][r + 1] * L2E - base);
                float p2 = exp2f(Sa[ct][r + 2] * L2E - base);
                float p3 = exp2f(Sa[ct][r + 3] * L2E - base);
                Sa[ct][r] = p0; Sa[ct][r + 1] = p1; Sa[ct][r + 2] = p2; Sa[ct][r + 3] = p3;
                s0 += p0; s1 += p1; s2 += p2; s3 += p3;
            }
        float sum = (s0 + s1) + (s2 + s3);
        sum += __shfl_xor(sum, 32, 64);
        float alpha = exp2f(m_r * L2E - base);
        l_r = l_r * alpha + sum;
        m_r = mnew;
#pragma unroll
        for (int dt = 0; dt < 2; ++dt)
#pragma unroll
            for (int r = 0; r < 16; ++r) Oa[dt][r] *= alpha;

        // ---- P -> B-operand frags: cvt_pk + permlane32_swap (no LDS round-trip) ----
        short8 pfr[2][2];
#pragma unroll
        for (int ct = 0; ct < 2; ++ct) {
            unsigned w0 = cvtpk(Sa[ct][0],  Sa[ct][1]);
            unsigned w2 = cvtpk(Sa[ct][4],  Sa[ct][5]);
            unsigned w1 = cvtpk(Sa[ct][2],  Sa[ct][3]);
            unsigned w3 = cvtpk(Sa[ct][6],  Sa[ct][7]);
            plswap(w0, w2);
            plswap(w1, w3);
            union { uintx4 u; short8 s; } cv0;
            cv0.u = (uintx4){w0, w1, w2, w3};
            pfr[ct][0] = cv0.s;
            unsigned x0 = cvtpk(Sa[ct][8],  Sa[ct][9]);
            unsigned x2 = cvtpk(Sa[ct][12], Sa[ct][13]);
            unsigned x1 = cvtpk(Sa[ct][10], Sa[ct][11]);
            unsigned x3 = cvtpk(Sa[ct][14], Sa[ct][15]);
            plswap(x0, x2);
            plswap(x1, x3);
            union { uintx4 u; short8 s; } cv1;
            cv1.u = (uintx4){x0, x1, x2, x3};
            pfr[ct][1] = cv1.s;
        }
        // ---- O^T += V^T · P^T ----
#pragma unroll
        for (int ct = 0; ct < 2; ++ct)
#pragma unroll
            for (int ks = 0; ks < 2; ++ks) {
                int keyb = ct * 32 + ks * 16 + hi * 8;
#pragma unroll
                for (int dt = 0; dt < 2; ++dt) {
                    short8 vf = *(const short8*)(Vs + (dt * 32 + qcol) * 72 + keyb);
                    Oa[dt] = __builtin_amdgcn_mfma_f32_32x32x16_bf16(vf, pfr[ct][ks], Oa[dt], 0, 0, 0);
                }
            }
    }
    // ---- epilogue: O^T / l -> per-wave LDS transpose -> coalesced bf16 rows ----
    __syncthreads();                       // all waves done with Ks/Vs
    short* Ow = smem + wave * 2304;        // [32 q][72]
    float inv = 1.f / l_r;
#pragma unroll
    for (int dt = 0; dt < 2; ++dt)
#pragma unroll
        for (int r = 0; r < 16; ++r) {
            int d = dt * 32 + (r & 3) + 8 * (r >> 2) + 4 * hi;
            Ow[qcol * 72 + d] = f2bf(Oa[dt][r] * inv);
        }
    int b = bh >> 4, h = bh & 15;
    int row = lane >> 1, doff = (lane & 1) * 32;
    int qa = q0 + wave * 32 + row;
    short* dst = ab + ((size_t)(b * SS + qa)) * EE + h * DD + doff;
    const short* srcr = Ow + row * 72 + doff;
    *(short8*)(dst)      = *(const short8*)(srcr);
    *(short8*)(dst + 8)  = *(const short8*)(srcr + 8);
    *(short8*)(dst + 16) = *(const short8*)(srcr + 16);
    *(short8*)(dst + 24) = *(const short8*)(srcr + 24);
}

extern "C" void kernel_launch(void* const* d_in, const int* in_sizes, int n_in,
                              void* d_out, int out_size, void* d_ws, size_t ws_size,
                              hipStream_t stream) {
    const float* x      = (const float*)d_in[0];
    const float* past   = (const float*)d_in[1];
    const float* w_attn = (const float*)d_in[2];
    const float* b_attn = (const float*)d_in[3];
    const float* w_proj = (const float*)d_in[4];
    const float* b_proj = (const float*)d_in[5];
    float* out = (float*)d_out;
    float* present = out + (size_t)BB * SS * EE;

    // workspace (bf16 staging), 64 MiB total
    short* ws  = (short*)d_ws;
    short* xb  = ws;                 // [4096][1024]            4,194,304
    short* wab = xb  + 4194304;      // w_attn^T [3072][1024]   3,145,728
    short* wpb = wab + 3145728;      // w_proj^T [1024][1024]   1,048,576
    short* qb  = wpb + 1048576;      // q [B,H,S,D] prescaled   4,194,304
    short* kbp = qb  + 4194304;      // K [B,H,NS,D]            8,388,608
    short* vbp = kbp + 8388608;      // V [B,H,NS,D]            8,388,608
    short* ab  = vbp + 8388608;      // attn out [B,S,E]        4,194,304

    cvt_copy_k<<<6144, 256, 0, stream>>>(x, past, xb, kbp, vbp, present);
    wtrans_k<<<1024, 256, 0, stream>>>(w_attn, w_proj, wab, wpb);
    gemm_bt_k<0><<<dim3(32, 24), 256, 0, stream>>>(xb, wab, b_attn, nullptr,
                                                   qb, kbp, vbp, present, E3);
    flash_attn_k<<<512, 256, 0, stream>>>(qb, kbp, vbp, ab);
    gemm_bt_k<1><<<dim3(32, 8), 256, 0, stream>>>(ab, wpb, b_proj, out,
                                                  nullptr, nullptr, nullptr, nullptr, EE);
}

// Round 3
// 302.383 us; speedup vs baseline: 1.4934x; 1.0306x over previous
//
#include <hip/hip_runtime.h>
#include <hip/hip_bf16.h>

#define BB 4
#define SS 1024
#define PP 1024
#define EE 1024
#define HH 16
#define DD 64
#define NS 2048          // P + S
#define E3 3072
#define VOFF 8388608     // element offset of V section in present [2,B,H,NS,D]
#define VPAST 4194304    // element offset of V section in layer_past [2,B,H,P,D]

typedef __attribute__((ext_vector_type(8))) short short8;
typedef __attribute__((ext_vector_type(4))) float floatx4;
typedef __attribute__((ext_vector_type(16))) float floatx16;
typedef __attribute__((ext_vector_type(4))) unsigned uintx4;

__device__ __forceinline__ short f2bf(float f) {
    return (short)(__bfloat16_as_ushort(__float2bfloat16(f)));
}

__device__ __forceinline__ unsigned cvtpk(float lo, float hi) {
    unsigned r;
    asm("v_cvt_pk_bf16_f32 %0, %1, %2" : "=v"(r) : "v"(lo), "v"(hi));
    return r;
}

__device__ __forceinline__ void plswap(unsigned &a, unsigned &b) {
    asm("v_permlane32_swap_b32 %0, %1" : "+v"(a), "+v"(b));
}

// async global->LDS, 16B per lane; lds ptr must be wave-uniform (HW: base + lane*16)
__device__ __forceinline__ void gload16(const void* g, void* l) {
    __builtin_amdgcn_global_load_lds(
        (const __attribute__((address_space(1))) void*)g,
        (__attribute__((address_space(3))) void*)l, 16, 0, 0);
}

// ---- cvt: x -> xb ; past K/V -> kb/vb bf16 AND present f32 past-slots (copy merged) ----
__global__ __launch_bounds__(256) void cvt_copy_k(
    const float* __restrict__ x, const float* __restrict__ past,
    short* __restrict__ xb, short* __restrict__ kbp, short* __restrict__ vbp,
    float* __restrict__ present)
{
    size_t e0 = ((size_t)blockIdx.x * 256 + threadIdx.x) * 8;
    if (e0 < 4194304) {                       // x [4096][1024]
        float4 a0 = *(const float4*)(x + e0);
        float4 a1 = *(const float4*)(x + e0 + 4);
        short8 s;
        s[0] = f2bf(a0.x); s[1] = f2bf(a0.y); s[2] = f2bf(a0.z); s[3] = f2bf(a0.w);
        s[4] = f2bf(a1.x); s[5] = f2bf(a1.y); s[6] = f2bf(a1.z); s[7] = f2bf(a1.w);
        *(short8*)(xb + e0) = s;
    } else {
        size_t r = e0 - 4194304;
        int sec = (r >= 4194304);             // 0: K, 1: V
        if (sec) r -= 4194304;
        const float* src = past + (sec ? VPAST : 0) + r;
        int row = (int)(r >> 6);              // bh*1024 + t
        int bh = row >> 10, t = row & 1023, d = (int)(r & 63);
        size_t off = ((size_t)bh * NS + t) * DD + d;
        float4 a0 = *(const float4*)src;
        float4 a1 = *(const float4*)(src + 4);
        short8 s;
        s[0] = f2bf(a0.x); s[1] = f2bf(a0.y); s[2] = f2bf(a0.z); s[3] = f2bf(a0.w);
        s[4] = f2bf(a1.x); s[5] = f2bf(a1.y); s[6] = f2bf(a1.z); s[7] = f2bf(a1.w);
        *(short8*)((sec ? vbp : kbp) + off) = s;
        float* pd = present + (sec ? VOFF : 0) + off;
        *(float4*)(pd)     = a0;
        *(float4*)(pd + 4) = a1;
    }
}

// ---------------- weight transpose+cvt: W[K,N] f32 -> Wt[N,K] bf16 (64x64 LDS tiles) ----
__global__ __launch_bounds__(256) void wtrans_k(
    const float* __restrict__ wa, const float* __restrict__ wp,
    short* __restrict__ wab, short* __restrict__ wpb)
{
    __shared__ short Ts[64][72];
    int bid = blockIdx.x;
    const float* src; short* dst; int n0, k0, Nsrc;
    if (bid < 768) { k0 = (bid & 15) * 64; n0 = (bid >> 4) * 64; src = wa; dst = wab; Nsrc = E3; }
    else { bid -= 768; k0 = (bid & 15) * 64; n0 = (bid >> 4) * 64; src = wp; dst = wpb; Nsrc = EE; }
    int tid = threadIdx.x;
    int r = tid >> 2, c = (tid & 3) * 16;
    const float* s = src + (size_t)(k0 + r) * Nsrc + n0 + c;
    float4 a0 = *(const float4*)(s);
    float4 a1 = *(const float4*)(s + 4);
    float4 a2 = *(const float4*)(s + 8);
    float4 a3 = *(const float4*)(s + 12);
    Ts[c +  0][r] = f2bf(a0.x); Ts[c +  1][r] = f2bf(a0.y);
    Ts[c +  2][r] = f2bf(a0.z); Ts[c +  3][r] = f2bf(a0.w);
    Ts[c +  4][r] = f2bf(a1.x); Ts[c +  5][r] = f2bf(a1.y);
    Ts[c +  6][r] = f2bf(a1.z); Ts[c +  7][r] = f2bf(a1.w);
    Ts[c +  8][r] = f2bf(a2.x); Ts[c +  9][r] = f2bf(a2.y);
    Ts[c + 10][r] = f2bf(a2.z); Ts[c + 11][r] = f2bf(a2.w);
    Ts[c + 12][r] = f2bf(a3.x); Ts[c + 13][r] = f2bf(a3.y);
    Ts[c + 14][r] = f2bf(a3.z); Ts[c + 15][r] = f2bf(a3.w);
    __syncthreads();
    int n = tid >> 2, kc = (tid & 3) * 16;
    short8 v0 = *(const short8*)&Ts[n][kc];
    short8 v1 = *(const short8*)&Ts[n][kc + 8];
    short* d = dst + (size_t)(n0 + n) * EE + k0 + kc;    // K == 1024 for both weights
    *(short8*)d = v0;
    *(short8*)(d + 8) = v1;
}

// ---------------- GEMM (m97-style): C = A[M,1024] @ Bt[N,1024]^T + bias -----------------
// NT = n-tile (128 or 64). m-tile fixed 128.
template<int MODE, int NT>
__global__ __launch_bounds__(256) void gemm_bt_k(
    const short* __restrict__ A,
    const short* __restrict__ Bt,
    const float* __restrict__ bias,
    float* __restrict__ outf,
    short* __restrict__ qb, short* __restrict__ kbp, short* __restrict__ vbp,
    float* __restrict__ present,
    int N)
{
    constexpr int MR = (NT == 128) ? 4 : 2;      // per-wave m fragment reps
    __shared__ __align__(16) short As[128 * 32];
    __shared__ __align__(16) short Bs[NT * 32];
    int tid = threadIdx.x;
    int wave = tid >> 6, lane = tid & 63;
    int fr = lane & 15, quad = lane >> 4;
    int wm = (NT == 128) ? (wave >> 1) : wave;
    int wn = (NT == 128) ? (wave & 1) : 0;
    // XCD-chunked bijective swizzle (nwg % 8 == 0)
    int hw = blockIdx.y * gridDim.x + blockIdx.x;
    int nwg = gridDim.x * gridDim.y;
    int work = (hw & 7) * (nwg >> 3) + (hw >> 3);
    int bx = work / gridDim.y, by = work - bx * gridDim.y;
    int m0 = bx * 128, n0 = by * NT;

    floatx4 acc[MR][4];
#pragma unroll
    for (int m = 0; m < MR; ++m)
#pragma unroll
        for (int n = 0; n < 4; ++n) acc[m][n] = (floatx4){0.f, 0.f, 0.f, 0.f};

    for (int k0 = 0; k0 < 1024; k0 += 32) {
        __syncthreads();
#pragma unroll
        for (int p = 0; p < 2; ++p) {
            int idx = p * 256 + tid;
            int row = idx >> 2, ch = idx & 3;
            gload16(A + (size_t)(m0 + row) * 1024 + k0 + ch * 8,
                    As + (p * 256 + wave * 64) * 8);
        }
#pragma unroll
        for (int p = 0; p < NT / 64; ++p) {
            int idx = p * 256 + tid;
            int row = idx >> 2, ch = idx & 3;
            gload16(Bt + (size_t)(n0 + row) * 1024 + k0 + ch * 8,
                    Bs + (p * 256 + wave * 64) * 8);
        }
        __syncthreads();
        short8 af[MR], bf[4];
#pragma unroll
        for (int m = 0; m < MR; ++m)
            af[m] = *(const short8*)(As + (wm * (MR * 16) + m * 16 + fr) * 32 + quad * 8);
#pragma unroll
        for (int n = 0; n < 4; ++n)
            bf[n] = *(const short8*)(Bs + (wn * 64 + n * 16 + fr) * 32 + quad * 8);
#pragma unroll
        for (int m = 0; m < MR; ++m)
#pragma unroll
            for (int n = 0; n < 4; ++n)
                acc[m][n] = __builtin_amdgcn_mfma_f32_16x16x32_bf16(af[m], bf[n], acc[m][n], 0, 0, 0);
    }
#pragma unroll
    for (int n = 0; n < 4; ++n) {
        int gc = n0 + wn * 64 + n * 16 + fr;
        float bv = bias[gc];
#pragma unroll
        for (int m = 0; m < MR; ++m) {
#pragma unroll
            for (int r = 0; r < 4; ++r) {
                int gr = m0 + wm * (MR * 16) + m * 16 + quad * 4 + r;
                float val = acc[m][n][r] + bv;
                if (MODE == 1) {
                    outf[(size_t)gr * N + gc] = val;
                } else {
                    int sec = gc >> 10, h = (gc >> 6) & 15, d = gc & 63;
                    int b = gr >> 10, sq = gr & 1023;
                    size_t bh = (size_t)(b * HH + h);
                    if (sec == 0) {
                        // fold 1/sqrt(D) * log2(e): S comes out of QK^T in log2 domain
                        qb[(bh * SS + sq) * DD + d] = f2bf(val * 0.18033688f);
                    } else {
                        size_t off = (bh * NS + PP + sq) * DD + d;
                        if (sec == 1) { present[off] = val;        kbp[off] = f2bf(val); }
                        else          { present[VOFF + off] = val; vbp[off] = f2bf(val); }
                    }
                }
            }
        }
    }
}

// ------------- flash attention: swapped-QK^T 32x32 MFMA, in-register softmax -------------
// Double-buffered K/V (one barrier/chunk), async-STAGE split (issue-early/write-late, T14),
// XOR-swizzled Ks AND Vs, defer-max (T13), S in log2 domain (log2e folded into Q).
__global__ __launch_bounds__(256) void flash_attn_k(
    const short* __restrict__ qb, const short* __restrict__ kbp,
    const short* __restrict__ vbp, short* __restrict__ ab)
{
    __shared__ __align__(16) short smem[16384];  // 32 KB: Ks[2][4096] | Vs[2][4096]
    short* Ks = smem;
    short* Vs = smem + 8192;

    int tid = threadIdx.x;
    int wave = tid >> 6, lane = tid & 63;
    int qcol = lane & 31, hi = lane >> 5;

    // XCD-chunked swizzle: XCD n -> bh in [n*8, n*8+8) (4 MB K/V per XCD L2)
    int bid = blockIdx.x;
    int work = (bid & 7) * 64 + (bid >> 3);
    int bh = work >> 3;
    int q0 = (work & 7) * 128;

    // Q^T B-fragments: lane holds Q[q = qcol][d = d0*16 + hi*8 + e], prescaled by 0.125*log2e
    const short* qrow = qb + ((size_t)bh * SS + q0 + wave * 32 + qcol) * DD + hi * 8;
    short8 qf[4];
#pragma unroll
    for (int i = 0; i < 4; ++i) qf[i] = *(const short8*)(qrow + i * 16);

    const short* kbase = kbp + (size_t)bh * NS * DD;
    const short* vbase = vbp + (size_t)bh * NS * DD;

    float m_r = -1e30f, l_r = 0.f;
    floatx16 Oa[2];
#pragma unroll
    for (int dt = 0; dt < 2; ++dt)
#pragma unroll
        for (int r = 0; r < 16; ++r) Oa[dt][r] = 0.f;

    int vkey = lane, vd0 = (tid >> 6) * 16;
    int qminw = PP + q0 + wave * 32;
    int qmaxw = qminw + 31;

    int nchunks = 18 + (q0 >> 6);
    short8 vs0, vs1;   // V(c+1) in flight across compute(c)

    // K issue: linear LDS dest, inverse-swizzled global source (always in-bounds: ws regions follow)
    auto KISSUE = [&](int cc, int bufi) {
        const short* kc = kbase + (size_t)cc * 64 * DD;
        short* Kd = Ks + bufi * 4096;
#pragma unroll
        for (int p = 0; p < 2; ++p) {
            int idx = p * 256 + tid;
            int row = idx >> 3, ch = idx & 7;
            gload16(kc + row * 64 + ((ch ^ (row & 7)) * 8), Kd + (p * 256 + wave * 64) * 8);
        }
    };
    auto VLOAD = [&](int cc) {
        const short* src = vbase + ((size_t)cc * 64 + vkey) * DD + vd0;
        vs0 = *(const short8*)src;
        vs1 = *(const short8*)(src + 8);
    };
    auto VWRITE = [&](int bufi) {
        short* Vd = Vs + bufi * 4096;
#pragma unroll
        for (int i = 0; i < 8; ++i) {
            int d0i = vd0 + i, d1i = vd0 + 8 + i;
            Vd[d0i * 64 + (((vkey >> 3) ^ (d0i & 7)) << 3) + (vkey & 7)] = vs0[i];
            Vd[d1i * 64 + (((vkey >> 3) ^ (d1i & 7)) << 3) + (vkey & 7)] = vs1[i];
        }
    };

    KISSUE(0, 0); VLOAD(0); VWRITE(0);
    __syncthreads();

    for (int c = 0; c < nchunks; ++c) {
        int t0 = c * 64;
        int cur = c & 1;
        KISSUE(c + 1, cur ^ 1);       // issue next-chunk loads early (hide under compute)
        VLOAD(c + 1);
        if (t0 <= qmaxw) {
            const short* Kc = Ks + cur * 4096;
            const short* Vc = Vs + cur * 4096;
            // ---- S^T[key][q] = K·Q^T (log2 domain) ----
            floatx16 Sa[2];
#pragma unroll
            for (int ct = 0; ct < 2; ++ct)
#pragma unroll
                for (int r = 0; r < 16; ++r) Sa[ct][r] = 0.f;
#pragma unroll
            for (int ct = 0; ct < 2; ++ct) {
                int key = ct * 32 + qcol;
                int rbase = key * 64, rx = key & 7;
#pragma unroll
                for (int d0 = 0; d0 < 4; ++d0) {
                    short8 kf = *(const short8*)(Kc + rbase + (((d0 * 2 + hi) ^ rx) * 8));
                    Sa[ct] = __builtin_amdgcn_mfma_f32_32x32x16_bf16(kf, qf[d0], Sa[ct], 0, 0, 0);
                }
            }
            // causal mask (only near-diagonal chunks)
            if (t0 + 63 > qminw) {
                int qa = qminw + qcol;
#pragma unroll
                for (int ct = 0; ct < 2; ++ct)
#pragma unroll
                    for (int r = 0; r < 16; ++r) {
                        int ka = t0 + ct * 32 + (r & 3) + 8 * (r >> 2) + 4 * hi;
                        if (ka > qa) Sa[ct][r] = -1e30f;
                    }
            }
            // ---- in-register online softmax; defer-max (THR = 8 nats = 11.54 log2) ----
            float mx0 = Sa[0][0], mx1 = Sa[0][1], mx2 = Sa[0][2], mx3 = Sa[0][3];
#pragma unroll
            for (int ct = 0; ct < 2; ++ct)
#pragma unroll
                for (int r = (ct ? 0 : 4); r < 16; r += 4) {
                    mx0 = fmaxf(mx0, Sa[ct][r]);
                    mx1 = fmaxf(mx1, Sa[ct][r + 1]);
                    mx2 = fmaxf(mx2, Sa[ct][r + 2]);
                    mx3 = fmaxf(mx3, Sa[ct][r + 3]);
                }
            float mx = fmaxf(fmaxf(mx0, mx1), fmaxf(mx2, mx3));
            mx = fmaxf(mx, __shfl_xor(mx, 32, 64));
            if (!__all(mx <= m_r + 11.5416f)) {
                float mnew = fmaxf(m_r, mx);
                float al = exp2f(m_r - mnew);
                l_r *= al;
#pragma unroll
                for (int dt = 0; dt < 2; ++dt)
#pragma unroll
                    for (int r = 0; r < 16; ++r) Oa[dt][r] *= al;
                m_r = mnew;
            }
            float s0 = 0.f, s1 = 0.f, s2 = 0.f, s3 = 0.f;
#pragma unroll
            for (int ct = 0; ct < 2; ++ct)
#pragma unroll
                for (int r = 0; r < 16; r += 4) {
                    float p0 = exp2f(Sa[ct][r]     - m_r);
                    float p1 = exp2f(Sa[ct][r + 1] - m_r);
                    float p2 = exp2f(Sa[ct][r + 2] - m_r);
                    float p3 = exp2f(Sa[ct][r + 3] - m_r);
                    Sa[ct][r] = p0; Sa[ct][r + 1] = p1; Sa[ct][r + 2] = p2; Sa[ct][r + 3] = p3;
                    s0 += p0; s1 += p1; s2 += p2; s3 += p3;
                }
            float sum = (s0 + s1) + (s2 + s3);
            sum += __shfl_xor(sum, 32, 64);
            l_r += sum;
            // ---- P -> B-operand frags: cvt_pk + permlane32_swap (no LDS round-trip) ----
            short8 pfr[2][2];
#pragma unroll
            for (int ct = 0; ct < 2; ++ct) {
                unsigned w0 = cvtpk(Sa[ct][0],  Sa[ct][1]);
                unsigned w2 = cvtpk(Sa[ct][4],  Sa[ct][5]);
                unsigned w1 = cvtpk(Sa[ct][2],  Sa[ct][3]);
                unsigned w3 = cvtpk(Sa[ct][6],  Sa[ct][7]);
                plswap(w0, w2);
                plswap(w1, w3);
                union { uintx4 u; short8 s; } cv0;
                cv0.u = (uintx4){w0, w1, w2, w3};
                pfr[ct][0] = cv0.s;
                unsigned x0 = cvtpk(Sa[ct][8],  Sa[ct][9]);
                unsigned x2 = cvtpk(Sa[ct][12], Sa[ct][13]);
                unsigned x1 = cvtpk(Sa[ct][10], Sa[ct][11]);
                unsigned x3 = cvtpk(Sa[ct][14], Sa[ct][15]);
                plswap(x0, x2);
                plswap(x1, x3);
                union { uintx4 u; short8 s; } cv1;
                cv1.u = (uintx4){x0, x1, x2, x3};
                pfr[ct][1] = cv1.s;
            }
            // ---- O^T += V^T · P^T ----
#pragma unroll
            for (int ct = 0; ct < 2; ++ct)
#pragma unroll
                for (int ks = 0; ks < 2; ++ks) {
                    int chunkb = ct * 4 + ks * 2 + hi;
#pragma unroll
                    for (int dt = 0; dt < 2; ++dt) {
                        int row = dt * 32 + qcol;
                        short8 vf = *(const short8*)(Vc + row * 64 + ((chunkb ^ (row & 7)) << 3));
                        Oa[dt] = __builtin_amdgcn_mfma_f32_32x32x16_bf16(vf, pfr[ct][ks], Oa[dt], 0, 0, 0);
                    }
                }
        }
        VWRITE(cur ^ 1);              // vmcnt wait for vs0/vs1 lands here, after compute
        __syncthreads();
    }
    // ---- epilogue: O^T / l -> per-wave LDS transpose -> coalesced bf16 rows ----
    short* Ow = smem + wave * 2304;   // [32 q][72]; safe: loop ended with barrier
    float inv = 1.f / l_r;
#pragma unroll
    for (int dt = 0; dt < 2; ++dt)
#pragma unroll
        for (int r = 0; r < 16; ++r) {
            int d = dt * 32 + (r & 3) + 8 * (r >> 2) + 4 * hi;
            Ow[qcol * 72 + d] = f2bf(Oa[dt][r] * inv);
        }
    int b = bh >> 4, h = bh & 15;
    int row = lane >> 1, doff = (lane & 1) * 32;
    int qa = q0 + wave * 32 + row;
    short* dst = ab + ((size_t)(b * SS + qa)) * EE + h * DD + doff;
    const short* srcr = Ow + row * 72 + doff;
    *(short8*)(dst)      = *(const short8*)(srcr);
    *(short8*)(dst + 8)  = *(const short8*)(srcr + 8);
    *(short8*)(dst + 16) = *(const short8*)(srcr + 16);
    *(short8*)(dst + 24) = *(const short8*)(srcr + 24);
}

extern "C" void kernel_launch(void* const* d_in, const int* in_sizes, int n_in,
                              void* d_out, int out_size, void* d_ws, size_t ws_size,
                              hipStream_t stream) {
    const float* x      = (const float*)d_in[0];
    const float* past   = (const float*)d_in[1];
    const float* w_attn = (const float*)d_in[2];
    const float* b_attn = (const float*)d_in[3];
    const float* w_proj = (const float*)d_in[4];
    const float* b_proj = (const float*)d_in[5];
    float* out = (float*)d_out;
    float* present = out + (size_t)BB * SS * EE;

    // workspace (bf16 staging), ~67 MiB total
    short* ws  = (short*)d_ws;
    short* xb  = ws;                 // [4096][1024]            4,194,304
    short* wab = xb  + 4194304;      // w_attn^T [3072][1024]   3,145,728
    short* wpb = wab + 3145728;      // w_proj^T [1024][1024]   1,048,576
    short* qb  = wpb + 1048576;      // q [B,H,S,D] prescaled   4,194,304
    short* kbp = qb  + 4194304;      // K [B,H,NS,D]            8,388,608
    short* vbp = kbp + 8388608;      // V [B,H,NS,D]            8,388,608
    short* ab  = vbp + 8388608;      // attn out [B,S,E]        4,194,304

    cvt_copy_k<<<6144, 256, 0, stream>>>(x, past, xb, kbp, vbp, present);
    wtrans_k<<<1024, 256, 0, stream>>>(w_attn, w_proj, wab, wpb);
    gemm_bt_k<0, 128><<<dim3(32, 24), 256, 0, stream>>>(xb, wab, b_attn, nullptr,
                                                        qb, kbp, vbp, present, E3);
    flash_attn_k<<<512, 256, 0, stream>>>(qb, kbp, vbp, ab);
    gemm_bt_k<1, 64><<<dim3(32, 16), 256, 0, stream>>>(ab, wpb, b_proj, out,
                                                       nullptr, nullptr, nullptr, nullptr, EE);
}

// Round 4
// 297.486 us; speedup vs baseline: 1.5180x; 1.0165x over previous
//
#include <hip/hip_runtime.h>
#include <hip/hip_bf16.h>

#define BB 4
#define SS 1024
#define PP 1024
#define EE 1024
#define HH 16
#define DD 64
#define NS 2048          // P + S
#define E3 3072
#define VOFF 8388608     // element offset of V section in present [2,B,H,NS,D]
#define VPAST 4194304    // element offset of V section in layer_past [2,B,H,P,D]

typedef __attribute__((ext_vector_type(8))) short short8;
typedef __attribute__((ext_vector_type(4))) float floatx4;
typedef __attribute__((ext_vector_type(16))) float floatx16;
typedef __attribute__((ext_vector_type(4))) unsigned uintx4;

__device__ __forceinline__ short f2bf(float f) {
    return (short)(__bfloat16_as_ushort(__float2bfloat16(f)));
}

__device__ __forceinline__ unsigned cvtpk(float lo, float hi) {
    unsigned r;
    asm("v_cvt_pk_bf16_f32 %0, %1, %2" : "=v"(r) : "v"(lo), "v"(hi));
    return r;
}

__device__ __forceinline__ void plswap(unsigned &a, unsigned &b) {
    asm("v_permlane32_swap_b32 %0, %1" : "+v"(a), "+v"(b));
}

// async global->LDS, 16B per lane; lds ptr must be wave-uniform (HW: base + lane*16)
__device__ __forceinline__ void gload16(const void* g, void* l) {
    __builtin_amdgcn_global_load_lds(
        (const __attribute__((address_space(1))) void*)g,
        (__attribute__((address_space(3))) void*)l, 16, 0, 0);
}

// ---- cvt: x -> xb ; past K/V -> kb/vb bf16 AND present f32 past-slots (copy merged) ----
__global__ __launch_bounds__(256) void cvt_copy_k(
    const float* __restrict__ x, const float* __restrict__ past,
    short* __restrict__ xb, short* __restrict__ kbp, short* __restrict__ vbp,
    float* __restrict__ present)
{
    size_t e0 = ((size_t)blockIdx.x * 256 + threadIdx.x) * 8;
    if (e0 < 4194304) {                       // x [4096][1024]
        float4 a0 = *(const float4*)(x + e0);
        float4 a1 = *(const float4*)(x + e0 + 4);
        short8 s;
        s[0] = f2bf(a0.x); s[1] = f2bf(a0.y); s[2] = f2bf(a0.z); s[3] = f2bf(a0.w);
        s[4] = f2bf(a1.x); s[5] = f2bf(a1.y); s[6] = f2bf(a1.z); s[7] = f2bf(a1.w);
        *(short8*)(xb + e0) = s;
    } else {
        size_t r = e0 - 4194304;
        int sec = (r >= 4194304);             // 0: K, 1: V
        if (sec) r -= 4194304;
        const float* src = past + (sec ? VPAST : 0) + r;
        int row = (int)(r >> 6);              // bh*1024 + t
        int bh = row >> 10, t = row & 1023, d = (int)(r & 63);
        size_t off = ((size_t)bh * NS + t) * DD + d;
        float4 a0 = *(const float4*)src;
        float4 a1 = *(const float4*)(src + 4);
        short8 s;
        s[0] = f2bf(a0.x); s[1] = f2bf(a0.y); s[2] = f2bf(a0.z); s[3] = f2bf(a0.w);
        s[4] = f2bf(a1.x); s[5] = f2bf(a1.y); s[6] = f2bf(a1.z); s[7] = f2bf(a1.w);
        *(short8*)((sec ? vbp : kbp) + off) = s;
        float* pd = present + (sec ? VOFF : 0) + off;
        *(float4*)(pd)     = a0;
        *(float4*)(pd + 4) = a1;
    }
}

// ---------------- weight transpose+cvt: W[K,N] f32 -> Wt[N,K] bf16 (64x64 LDS tiles) ----
__global__ __launch_bounds__(256) void wtrans_k(
    const float* __restrict__ wa, const float* __restrict__ wp,
    short* __restrict__ wab, short* __restrict__ wpb)
{
    __shared__ short Ts[64][72];
    int bid = blockIdx.x;
    const float* src; short* dst; int n0, k0, Nsrc;
    if (bid < 768) { k0 = (bid & 15) * 64; n0 = (bid >> 4) * 64; src = wa; dst = wab; Nsrc = E3; }
    else { bid -= 768; k0 = (bid & 15) * 64; n0 = (bid >> 4) * 64; src = wp; dst = wpb; Nsrc = EE; }
    int tid = threadIdx.x;
    int r = tid >> 2, c = (tid & 3) * 16;
    const float* s = src + (size_t)(k0 + r) * Nsrc + n0 + c;
    float4 a0 = *(const float4*)(s);
    float4 a1 = *(const float4*)(s + 4);
    float4 a2 = *(const float4*)(s + 8);
    float4 a3 = *(const float4*)(s + 12);
    Ts[c +  0][r] = f2bf(a0.x); Ts[c +  1][r] = f2bf(a0.y);
    Ts[c +  2][r] = f2bf(a0.z); Ts[c +  3][r] = f2bf(a0.w);
    Ts[c +  4][r] = f2bf(a1.x); Ts[c +  5][r] = f2bf(a1.y);
    Ts[c +  6][r] = f2bf(a1.z); Ts[c +  7][r] = f2bf(a1.w);
    Ts[c +  8][r] = f2bf(a2.x); Ts[c +  9][r] = f2bf(a2.y);
    Ts[c + 10][r] = f2bf(a2.z); Ts[c + 11][r] = f2bf(a2.w);
    Ts[c + 12][r] = f2bf(a3.x); Ts[c + 13][r] = f2bf(a3.y);
    Ts[c + 14][r] = f2bf(a3.z); Ts[c + 15][r] = f2bf(a3.w);
    __syncthreads();
    int n = tid >> 2, kc = (tid & 3) * 16;
    short8 v0 = *(const short8*)&Ts[n][kc];
    short8 v1 = *(const short8*)&Ts[n][kc + 8];
    short* d = dst + (size_t)(n0 + n) * EE + k0 + kc;    // K == 1024 for both weights
    *(short8*)d = v0;
    *(short8*)(d + 8) = v1;
}

// ------- GEMM: C = A[M,1024] @ Bt[N,1024]^T + bias. 2-phase LDS double-buffer (T3-min) ----
template<int MODE, int NT>
__global__ __launch_bounds__(256) void gemm_bt_k(
    const short* __restrict__ A,
    const short* __restrict__ Bt,
    const float* __restrict__ bias,
    float* __restrict__ outf,
    short* __restrict__ qb, short* __restrict__ kbp, short* __restrict__ vbp,
    float* __restrict__ present,
    int N)
{
    constexpr int MR = (NT == 128) ? 4 : 2;      // per-wave m fragment reps
    __shared__ __align__(16) short As[2][128 * 32];
    __shared__ __align__(16) short Bs[2][NT * 32];
    int tid = threadIdx.x;
    int wave = tid >> 6, lane = tid & 63;
    int fr = lane & 15, quad = lane >> 4;
    int wm = (NT == 128) ? (wave >> 1) : wave;
    int wn = (NT == 128) ? (wave & 1) : 0;
    // XCD-chunked bijective swizzle (nwg % 8 == 0)
    int hw = blockIdx.y * gridDim.x + blockIdx.x;
    int nwg = gridDim.x * gridDim.y;
    int work = (hw & 7) * (nwg >> 3) + (hw >> 3);
    int bx = work / gridDim.y, by = work - bx * gridDim.y;
    int m0 = bx * 128, n0 = by * NT;

    floatx4 acc[MR][4];
#pragma unroll
    for (int m = 0; m < MR; ++m)
#pragma unroll
        for (int n = 0; n < 4; ++n) acc[m][n] = (floatx4){0.f, 0.f, 0.f, 0.f};

    auto STAGE = [&](int k0, int buf) {
#pragma unroll
        for (int p = 0; p < 2; ++p) {
            int idx = p * 256 + tid;
            int row = idx >> 2, ch = idx & 3;
            gload16(A + (size_t)(m0 + row) * 1024 + k0 + ch * 8,
                    &As[buf][(p * 256 + wave * 64) * 8]);
        }
#pragma unroll
        for (int p = 0; p < NT / 64; ++p) {
            int idx = p * 256 + tid;
            int row = idx >> 2, ch = idx & 3;
            gload16(Bt + (size_t)(n0 + row) * 1024 + k0 + ch * 8,
                    &Bs[buf][(p * 256 + wave * 64) * 8]);
        }
    };

    STAGE(0, 0);
    __syncthreads();                       // drains vmcnt(0): tile 0 ready
    for (int k0 = 0; k0 < 1024; k0 += 32) {
        int cur = (k0 >> 5) & 1;
        if (k0 + 32 < 1024) STAGE(k0 + 32, cur ^ 1);   // issue next tile BEFORE compute
        short8 af[MR], bf[4];
#pragma unroll
        for (int m = 0; m < MR; ++m)
            af[m] = *(const short8*)(&As[cur][(wm * (MR * 16) + m * 16 + fr) * 32 + quad * 8]);
#pragma unroll
        for (int n = 0; n < 4; ++n)
            bf[n] = *(const short8*)(&Bs[cur][(wn * 64 + n * 16 + fr) * 32 + quad * 8]);
#pragma unroll
        for (int m = 0; m < MR; ++m)
#pragma unroll
            for (int n = 0; n < 4; ++n)
                acc[m][n] = __builtin_amdgcn_mfma_f32_16x16x32_bf16(af[m], bf[n], acc[m][n], 0, 0, 0);
        __syncthreads();                   // one vmcnt(0)+barrier per K-step, AFTER compute
    }
#pragma unroll
    for (int n = 0; n < 4; ++n) {
        int gc = n0 + wn * 64 + n * 16 + fr;
        float bv = bias[gc];
#pragma unroll
        for (int m = 0; m < MR; ++m) {
#pragma unroll
            for (int r = 0; r < 4; ++r) {
                int gr = m0 + wm * (MR * 16) + m * 16 + quad * 4 + r;
                float val = acc[m][n][r] + bv;
                if (MODE == 1) {
                    outf[(size_t)gr * N + gc] = val;
                } else {
                    int sec = gc >> 10, h = (gc >> 6) & 15, d = gc & 63;
                    int b = gr >> 10, sq = gr & 1023;
                    size_t bh = (size_t)(b * HH + h);
                    if (sec == 0) {
                        // fold 1/sqrt(D) * log2(e): S comes out of QK^T in log2 domain
                        qb[(bh * SS + sq) * DD + d] = f2bf(val * 0.18033688f);
                    } else {
                        size_t off = (bh * NS + PP + sq) * DD + d;
                        if (sec == 1) { present[off] = val;        kbp[off] = f2bf(val); }
                        else          { present[VOFF + off] = val; vbp[off] = f2bf(val); }
                    }
                }
            }
        }
    }
}

// ------------- flash attention: 8 waves, key-split pairs, in-register softmax -------------
// Wave w: q-group qg=w>>1 (32 q), key-half kh=w&1 (32 of each 64-key chunk).
// Private (m,l,O) per wave; merged once at the end. Doubles occupancy vs 4-wave version.
__global__ __launch_bounds__(512) void flash_attn_k(
    const short* __restrict__ qb, const short* __restrict__ kbp,
    const short* __restrict__ vbp, short* __restrict__ ab)
{
    __shared__ __align__(16) short smem[16384];  // 32 KB: Ks[2][4096] | Vs[2][4096]
    short* Ks = smem;
    short* Vs = smem + 8192;

    int tid = threadIdx.x;
    int wave = tid >> 6, lane = tid & 63;
    int qcol = lane & 31, hi = lane >> 5;
    int qg = wave >> 1, kh = wave & 1;

    // XCD-chunked swizzle: XCD n -> bh in [n*8, n*8+8) (4 MB K/V per XCD L2)
    int bid = blockIdx.x;
    int work = (bid & 7) * 64 + (bid >> 3);
    int bh = work >> 3;
    int q0 = (work & 7) * 128;

    // Q^T B-fragments: lane holds Q[q = qcol][d], prescaled by 0.125*log2e
    const short* qrow = qb + ((size_t)bh * SS + q0 + qg * 32 + qcol) * DD + hi * 8;
    short8 qf[4];
#pragma unroll
    for (int i = 0; i < 4; ++i) qf[i] = *(const short8*)(qrow + i * 16);

    const short* kbase = kbp + (size_t)bh * NS * DD;
    const short* vbase = vbp + (size_t)bh * NS * DD;

    float m_r = -1e30f, l_r = 0.f;
    floatx16 Oa[2];
#pragma unroll
    for (int dt = 0; dt < 2; ++dt)
#pragma unroll
        for (int r = 0; r < 16; ++r) Oa[dt][r] = 0.f;

    int vkey = tid & 63, vd0 = (tid >> 6) * 8;   // V staging: 8 d-rows per thread
    int qminw = PP + q0 + qg * 32;
    int qmaxw = qminw + 31;

    short8 vs0;
    auto KISSUE = [&](int cc, int bufi) {        // 512 lanes cover 64x64 in one shot
        const short* kc = kbase + (size_t)cc * 64 * DD;
        int row = tid >> 3, ch = tid & 7;
        gload16(kc + row * 64 + ((ch ^ (row & 7)) * 8),
                Ks + bufi * 4096 + wave * 512);
    };
    auto VLOAD = [&](int cc) {
        vs0 = *(const short8*)(vbase + ((size_t)cc * 64 + vkey) * DD + vd0);
    };
    auto VWRITE = [&](int bufi) {
        short* Vd = Vs + bufi * 4096;
#pragma unroll
        for (int i = 0; i < 8; ++i) {
            int di = vd0 + i;
            Vd[di * 64 + (((vkey >> 3) ^ (di & 7)) << 3) + (vkey & 7)] = vs0[i];
        }
    };

    int nchunks = 18 + (q0 >> 6);
    KISSUE(0, 0); VLOAD(0); VWRITE(0);
    __syncthreads();

    for (int c = 0; c < nchunks; ++c) {
        int t0 = c * 64;
        int cur = c & 1;
        if (c + 1 < nchunks) { KISSUE(c + 1, cur ^ 1); VLOAD(c + 1); }
        if (t0 <= qmaxw) {
            const short* Kc = Ks + cur * 4096;
            const short* Vc = Vs + cur * 4096;
            // ---- S^T[key][q] = K·Q^T (log2 domain), this wave's 32-key half ----
            floatx16 Sa;
#pragma unroll
            for (int r = 0; r < 16; ++r) Sa[r] = 0.f;
            int key = kh * 32 + qcol;
            int rbase = key * 64, rx = key & 7;
#pragma unroll
            for (int d0 = 0; d0 < 4; ++d0) {
                short8 kf = *(const short8*)(Kc + rbase + (((d0 * 2 + hi) ^ rx) * 8));
                Sa = __builtin_amdgcn_mfma_f32_32x32x16_bf16(kf, qf[d0], Sa, 0, 0, 0);
            }
            // causal mask (near-diagonal chunks only)
            if (t0 + 63 > qminw) {
                int qa = qminw + qcol;
#pragma unroll
                for (int r = 0; r < 16; ++r) {
                    int ka = t0 + kh * 32 + (r & 3) + 8 * (r >> 2) + 4 * hi;
                    if (ka > qa) Sa[r] = -1e30f;
                }
            }
            // ---- in-register online softmax; defer-max (THR = 8 nats = 11.54 log2) ----
            float mx0 = fmaxf(Sa[0], Sa[1]),  mx1 = fmaxf(Sa[2], Sa[3]);
            float mx2 = fmaxf(Sa[4], Sa[5]),  mx3 = fmaxf(Sa[6], Sa[7]);
            mx0 = fmaxf(mx0, fmaxf(Sa[8], Sa[9]));
            mx1 = fmaxf(mx1, fmaxf(Sa[10], Sa[11]));
            mx2 = fmaxf(mx2, fmaxf(Sa[12], Sa[13]));
            mx3 = fmaxf(mx3, fmaxf(Sa[14], Sa[15]));
            float mx = fmaxf(fmaxf(mx0, mx1), fmaxf(mx2, mx3));
            mx = fmaxf(mx, __shfl_xor(mx, 32, 64));
            if (!__all(mx <= m_r + 11.5416f)) {
                float mnew = fmaxf(m_r, mx);
                float al = exp2f(m_r - mnew);
                l_r *= al;
#pragma unroll
                for (int dt = 0; dt < 2; ++dt)
#pragma unroll
                    for (int r = 0; r < 16; ++r) Oa[dt][r] *= al;
                m_r = mnew;
            }
            float s0 = 0.f, s1 = 0.f, s2 = 0.f, s3 = 0.f;
#pragma unroll
            for (int r = 0; r < 16; r += 4) {
                float p0 = exp2f(Sa[r]     - m_r);
                float p1 = exp2f(Sa[r + 1] - m_r);
                float p2 = exp2f(Sa[r + 2] - m_r);
                float p3 = exp2f(Sa[r + 3] - m_r);
                Sa[r] = p0; Sa[r + 1] = p1; Sa[r + 2] = p2; Sa[r + 3] = p3;
                s0 += p0; s1 += p1; s2 += p2; s3 += p3;
            }
            float sum = (s0 + s1) + (s2 + s3);
            sum += __shfl_xor(sum, 32, 64);
            l_r += sum;
            // ---- P -> B-operand frags: cvt_pk + permlane32_swap ----
            short8 pfr[2];
            {
                unsigned w0 = cvtpk(Sa[0],  Sa[1]);
                unsigned w2 = cvtpk(Sa[4],  Sa[5]);
                unsigned w1 = cvtpk(Sa[2],  Sa[3]);
                unsigned w3 = cvtpk(Sa[6],  Sa[7]);
                plswap(w0, w2);
                plswap(w1, w3);
                union { uintx4 u; short8 s; } cv0;
                cv0.u = (uintx4){w0, w1, w2, w3};
                pfr[0] = cv0.s;
                unsigned x0 = cvtpk(Sa[8],  Sa[9]);
                unsigned x2 = cvtpk(Sa[12], Sa[13]);
                unsigned x1 = cvtpk(Sa[10], Sa[11]);
                unsigned x3 = cvtpk(Sa[14], Sa[15]);
                plswap(x0, x2);
                plswap(x1, x3);
                union { uintx4 u; short8 s; } cv1;
                cv1.u = (uintx4){x0, x1, x2, x3};
                pfr[1] = cv1.s;
            }
            // ---- O^T += V^T · P^T (this wave's 32-key half) ----
#pragma unroll
            for (int ks = 0; ks < 2; ++ks) {
                int chunkb = kh * 4 + ks * 2 + hi;
#pragma unroll
                for (int dt = 0; dt < 2; ++dt) {
                    int row = dt * 32 + qcol;
                    short8 vf = *(const short8*)(Vc + row * 64 + ((chunkb ^ (row & 7)) << 3));
                    Oa[dt] = __builtin_amdgcn_mfma_f32_32x32x16_bf16(vf, pfr[ks], Oa[dt], 0, 0, 0);
                }
            }
        }
        if (c + 1 < nchunks) VWRITE(cur ^ 1);
        __syncthreads();
    }

    // ---- merge key-half pairs: (m,l,O)_kh0 + (m,l,O)_kh1 ----
    float* mlf = (float*)smem;                   // [8 waves][32 q][2]
    if (hi == 0) {
        mlf[(wave * 32 + qcol) * 2]     = m_r;
        mlf[(wave * 32 + qcol) * 2 + 1] = l_r;
    }
    __syncthreads();
    float m_o = mlf[((wave ^ 1) * 32 + qcol) * 2];
    float l_o = mlf[((wave ^ 1) * 32 + qcol) * 2 + 1];
    __syncthreads();
    float M = fmaxf(m_r, m_o);
    float sc = exp2f(m_r - M);
    float l_tot = l_r * sc + l_o * exp2f(m_o - M);
    float* Of = (float*)smem;                    // [4 qg][64 d][32 q] f32 = 32 KB
    if (kh == 0) {
#pragma unroll
        for (int dt = 0; dt < 2; ++dt)
#pragma unroll
            for (int r = 0; r < 16; ++r) {
                int d = dt * 32 + (r & 3) + 8 * (r >> 2) + 4 * hi;
                Of[(qg * 64 + d) * 32 + qcol] = Oa[dt][r] * sc;
            }
    }
    __syncthreads();
    if (kh == 1) {
        float inv = 1.f / l_tot;
#pragma unroll
        for (int dt = 0; dt < 2; ++dt)
#pragma unroll
            for (int r = 0; r < 16; ++r) {
                int d = dt * 32 + (r & 3) + 8 * (r >> 2) + 4 * hi;
                Oa[dt][r] = (Of[(qg * 64 + d) * 32 + qcol] + Oa[dt][r] * sc) * inv;
            }
    }
    __syncthreads();
    short* Ot = smem;                            // [4 qg][32 q][72 d] bf16
    if (kh == 1) {
#pragma unroll
        for (int dt = 0; dt < 2; ++dt)
#pragma unroll
            for (int r = 0; r < 16; ++r) {
                int d = dt * 32 + (r & 3) + 8 * (r >> 2) + 4 * hi;
                Ot[(qg * 32 + qcol) * 72 + d] = f2bf(Oa[dt][r]);
            }
    }
    __syncthreads();
    // coalesced store: 512 threads x 32B
    int r2 = tid >> 2;                           // 0..127
    int qgi = r2 >> 5, qi = r2 & 31, doff = (tid & 3) * 16;
    int b = bh >> 4, h = bh & 15;
    int qa = q0 + qgi * 32 + qi;
    short* dst = ab + ((size_t)(b * SS + qa)) * EE + h * DD + doff;
    const short* srcr = Ot + (qgi * 32 + qi) * 72 + doff;
    *(short8*)(dst)     = *(const short8*)(srcr);
    *(short8*)(dst + 8) = *(const short8*)(srcr + 8);
}

extern "C" void kernel_launch(void* const* d_in, const int* in_sizes, int n_in,
                              void* d_out, int out_size, void* d_ws, size_t ws_size,
                              hipStream_t stream) {
    const float* x      = (const float*)d_in[0];
    const float* past   = (const float*)d_in[1];
    const float* w_attn = (const float*)d_in[2];
    const float* b_attn = (const float*)d_in[3];
    const float* w_proj = (const float*)d_in[4];
    const float* b_proj = (const float*)d_in[5];
    float* out = (float*)d_out;
    float* present = out + (size_t)BB * SS * EE;

    // workspace (bf16 staging), ~67 MiB total
    short* ws  = (short*)d_ws;
    short* xb  = ws;                 // [4096][1024]            4,194,304
    short* wab = xb  + 4194304;      // w_attn^T [3072][1024]   3,145,728
    short* wpb = wab + 3145728;      // w_proj^T [1024][1024]   1,048,576
    short* qb  = wpb + 1048576;      // q [B,H,S,D] prescaled   4,194,304
    short* kbp = qb  + 4194304;      // K [B,H,NS,D]            8,388,608
    short* vbp = kbp + 8388608;      // V [B,H,NS,D]            8,388,608
    short* ab  = vbp + 8388608;      // attn out [B,S,E]        4,194,304

    cvt_copy_k<<<6144, 256, 0, stream>>>(x, past, xb, kbp, vbp, present);
    wtrans_k<<<1024, 256, 0, stream>>>(w_attn, w_proj, wab, wpb);
    gemm_bt_k<0, 128><<<dim3(32, 24), 256, 0, stream>>>(xb, wab, b_attn, nullptr,
                                                        qb, kbp, vbp, present, E3);
    flash_attn_k<<<512, 512, 0, stream>>>(qb, kbp, vbp, ab);
    gemm_bt_k<1, 64><<<dim3(32, 16), 256, 0, stream>>>(ab, wpb, b_proj, out,
                                                       nullptr, nullptr, nullptr, nullptr, EE);
}